// Round 5
// baseline (3588.995 us; speedup 1.0000x reference)
//
#include <hip/hip_runtime.h>

#define N_ATOMS 131072
#define M_NBR 12
#define ORIG_F 92
#define AF 64
#define NCONV 3
#define N0_CRYS 1024
#define FIN 169
#define C2 128
#define KP 128                       // K of nbr-part GEMM: 64 nbr + 41 nbrf + pad
#define BN_EPS 1e-5f
#define TILES (N_ATOMS * M_NBR / 64) // 24576 tiles of 64 rows
#define GGRID 1536
#define ASTR 132                     // LDS row stride in f16 (264B -> 2-way bank alias, free)

typedef _Float16 f16;
typedef _Float16 half8 __attribute__((ext_vector_type(8)));
typedef float f32x4 __attribute__((ext_vector_type(4)));

__device__ __forceinline__ float sigmoidf_(float t) {
    return 1.0f / (1.0f + __expf(-t));
}
__device__ __forceinline__ float softplusf_(float t) {
    return fmaxf(t, 0.0f) + __logf(1.0f + __expf(-fabsf(t)));
}

// ---------------- embed: x = atom_fea @ W_embed + b (fp32 + f16 copies) ------
__global__ __launch_bounds__(256) void k_embed(const float* __restrict__ af,
                                               const float* __restrict__ W,
                                               const float* __restrict__ b,
                                               float* __restrict__ x,
                                               f16* __restrict__ xh) {
    int i = blockIdx.x * 256 + threadIdx.x;
    int n = i >> 6, f = i & 63;
    float acc = b[f];
    for (int k = 0; k < ORIG_F; ++k)
        acc = fmaf(af[(size_t)n * ORIG_F + k], W[k * AF + f], acc);
    x[i] = acc;
    xh[i] = (f16)acc;
}

// ---------------- cvt nbr_fea -> f16 padded [N*M][44] (run once) -------------
__global__ __launch_bounds__(256) void k_cvt_nbrf(const float* __restrict__ nf,
                                                  f16* __restrict__ nfh) {
    const int r0 = blockIdx.x * 16;
    for (int i = threadIdx.x; i < 16 * 44; i += 256) {
        int r = i / 44, k = i - r * 44;
        size_t row = (size_t)(r0 + r);
        nfh[row * 44 + k] = (k < 41) ? (f16)nf[row * 41 + k] : (f16)0.0f;
    }
}

// ---------------- selfout[n][c] = x[n]·W[0:64][c] + b[c]  (f16) --------------
__global__ __launch_bounds__(256) void k_selfW(const float* __restrict__ x,
                                               const float* __restrict__ W,
                                               const float* __restrict__ b,
                                               f16* __restrict__ selfout) {
    int i = blockIdx.x * 256 + threadIdx.x;   // i < N*128
    int n = i >> 7, c = i & 127;
    float acc = b[c];
    for (int k = 0; k < 64; ++k)
        acc = fmaf(x[(size_t)n * 64 + k], W[k * C2 + c], acc);
    selfout[i] = (f16)acc;
}

// ---------------- Wt2[c][k]: nbr-part W transposed, f16, K padded to 128 -----
__global__ __launch_bounds__(256) void k_prepW2(const float* __restrict__ W,
                                                f16* __restrict__ Wt2) {
    int i = blockIdx.x * 256 + threadIdx.x;   // i < 128*128
    if (i >= C2 * KP) return;
    int c = i >> 7, k = i & 127;
    // k<64 -> W row 64+k (neighbor); 64<=k<105 -> W row 128+(k-64)=64+k (nbr_fea)
    Wt2[i] = (k < 105) ? (f16)W[(k + 64) * C2 + c] : (f16)0.0f;
}

// ====== shared GEMM-tile machinery (pass 1: stats; pass 2: apply) ============
// block 256 = 4 waves; tile 64 rows x 128 cols; wave = (rhalf, chalf).
// A row r (global row gr=r0+r, atom gr/12, m gr%12) = [xh[nidx[gr]] | nfh[gr] | pad]
// acc += A @ Wt2^T ; epilogue adds selfout[atom][c].

__global__ __launch_bounds__(256) void k_gstats(const f16* __restrict__ xh,
                                                const f16* __restrict__ nfh,
                                                const int* __restrict__ nidx,
                                                const f16* __restrict__ Wt2,
                                                const f16* __restrict__ selfout,
                                                float* __restrict__ stats) {
    __shared__ unsigned short Ash[64 * ASTR];
    __shared__ unsigned short Sself[7 * 128];
    __shared__ float redS[128], redQ[128];

    const int tid = threadIdx.x;
    const int wv = tid >> 6, lane = tid & 63;
    const int quad = lane >> 4, l16 = lane & 15;
    const int rhalf = wv >> 1, c0w = (wv & 1) * 64;

    if (tid < 128) { redS[tid] = 0.0f; redQ[tid] = 0.0f; }
    // zero pad cols 108..127 once (finite; never rewritten)
    for (int i = tid; i < 64 * 5; i += 256) {
        int r = i / 5, t = i - r * 5;
        *(ushort4*)&Ash[r * ASTR + 108 + t * 4] = make_ushort4(0, 0, 0, 0);
    }

    half8 Bf[4][4];
    int cidx[4];
#pragma unroll
    for (int ct = 0; ct < 4; ++ct) {
        int c = c0w + ct * 16 + l16;
        cidx[ct] = c;
#pragma unroll
        for (int kc = 0; kc < 4; ++kc)
            Bf[kc][ct] = *(const half8*)&Wt2[c * KP + kc * 32 + quad * 8];
    }

    float ssum[4] = {0, 0, 0, 0}, ssq[4] = {0, 0, 0, 0};

    for (int rb = blockIdx.x; rb < TILES; rb += GGRID) {
        const int r0 = rb * 64;
        const int nf0 = r0 / 12, r0m = r0 - nf0 * 12;
        __syncthreads();
        // gathered neighbor rows: cols 0..63
        for (int i = tid; i < 64 * 16; i += 256) {
            int r = i >> 4, sg = i & 15;
            int gi = nidx[r0 + r];
            *(ushort4*)&Ash[r * ASTR + sg * 4] = *(const ushort4*)&xh[(size_t)gi * 64 + sg * 4];
        }
        // nbr_fea rows: cols 64..107
        for (int i = tid; i < 64 * 11; i += 256) {
            int r = i / 11, j = i - r * 11;
            *(ushort4*)&Ash[r * ASTR + 64 + j * 4] = *(const ushort4*)&nfh[(size_t)(r0 + r) * 44 + j * 4];
        }
        // selfout rows for this tile's atoms
        for (int i = tid; i < 7 * 32; i += 256) {
            int a = i >> 5, cc = i & 31;
            int n = min(nf0 + a, N_ATOMS - 1);
            *(ushort4*)&Sself[a * 128 + cc * 4] = *(const ushort4*)&selfout[(size_t)n * 128 + cc * 4];
        }
        __syncthreads();

        f32x4 acc[2][4];
#pragma unroll
        for (int rf = 0; rf < 2; ++rf)
#pragma unroll
            for (int ct = 0; ct < 4; ++ct) acc[rf][ct] = (f32x4){0, 0, 0, 0};
#pragma unroll
        for (int kc = 0; kc < 4; ++kc) {
            half8 a0 = *(half8*)&Ash[(rhalf * 32 + l16) * ASTR + kc * 32 + quad * 8];
            half8 a1 = *(half8*)&Ash[(rhalf * 32 + 16 + l16) * ASTR + kc * 32 + quad * 8];
#pragma unroll
            for (int ct = 0; ct < 4; ++ct) {
                acc[0][ct] = __builtin_amdgcn_mfma_f32_16x16x32_f16(a0, Bf[kc][ct], acc[0][ct], 0, 0, 0);
                acc[1][ct] = __builtin_amdgcn_mfma_f32_16x16x32_f16(a1, Bf[kc][ct], acc[1][ct], 0, 0, 0);
            }
        }
        // stats epilogue (registers only)
#pragma unroll
        for (int rf = 0; rf < 2; ++rf) {
            int rl0 = rhalf * 32 + rf * 16 + quad * 4;
#pragma unroll
            for (int ct = 0; ct < 4; ++ct) {
#pragma unroll
                for (int e = 0; e < 4; ++e) {
                    int al = (rl0 + e + r0m) / 12;
                    float v = acc[rf][ct][e] + (float)((f16*)Sself)[al * 128 + cidx[ct]];
                    ssum[ct] += v;
                    ssq[ct] = fmaf(v, v, ssq[ct]);
                }
            }
        }
    }

    // block reduce + global atomics
#pragma unroll
    for (int ct = 0; ct < 4; ++ct) {
        float s = ssum[ct], q = ssq[ct];
        s += __shfl_xor(s, 16); s += __shfl_xor(s, 32);
        q += __shfl_xor(q, 16); q += __shfl_xor(q, 32);
        if (quad == 0) {
            atomicAdd(&redS[cidx[ct]], s);
            atomicAdd(&redQ[cidx[ct]], q);
        }
    }
    __syncthreads();
    if (tid < 128) {
        atomicAdd(&stats[tid], redS[tid]);
        atomicAdd(&stats[128 + tid], redQ[tid]);
    }
}

__global__ __launch_bounds__(256) void k_gapply(const f16* __restrict__ xh,
                                                const f16* __restrict__ nfh,
                                                const int* __restrict__ nidx,
                                                const f16* __restrict__ Wt2,
                                                const f16* __restrict__ selfout,
                                                const float* __restrict__ g1,
                                                const float* __restrict__ be1,
                                                const float* __restrict__ stats,
                                                float* __restrict__ ns) {
    __shared__ unsigned short U[64 * ASTR];   // union: Ash, then P1(64x64)|P2(64x64)
    __shared__ unsigned short Sself[7 * 128];

    const int tid = threadIdx.x;
    const int wv = tid >> 6, lane = tid & 63;
    const int quad = lane >> 4, l16 = lane & 15;
    const int rhalf = wv >> 1, c0w = (wv & 1) * 64;
    f16* P1 = (f16*)U;
    f16* P2 = (f16*)U + 4096;

    for (int i = tid; i < 64 * 5; i += 256) {
        int r = i / 5, t = i - r * 5;
        *(ushort4*)&U[r * ASTR + 108 + t * 4] = make_ushort4(0, 0, 0, 0);
    }

    const float invc = 1.0f / ((float)N_ATOMS * M_NBR);
    half8 Bf[4][4];
    int cidx[4];
    float Aff[4], Bff[4];
#pragma unroll
    for (int ct = 0; ct < 4; ++ct) {
        int c = c0w + ct * 16 + l16;
        cidx[ct] = c;
        float mean = stats[c] * invc;
        float var = stats[128 + c] * invc - mean * mean;
        float Ai = g1[c] * rsqrtf(var + BN_EPS);
        Aff[ct] = Ai;
        Bff[ct] = be1[c] - Ai * mean;
#pragma unroll
        for (int kc = 0; kc < 4; ++kc)
            Bf[kc][ct] = *(const half8*)&Wt2[c * KP + kc * 32 + quad * 8];
    }

    for (int rb = blockIdx.x; rb < TILES; rb += GGRID) {
        const int r0 = rb * 64;
        const int nf0 = r0 / 12, r0m = r0 - nf0 * 12;
        __syncthreads();
        for (int i = tid; i < 64 * 16; i += 256) {
            int r = i >> 4, sg = i & 15;
            int gi = nidx[r0 + r];
            *(ushort4*)&U[r * ASTR + sg * 4] = *(const ushort4*)&xh[(size_t)gi * 64 + sg * 4];
        }
        for (int i = tid; i < 64 * 11; i += 256) {
            int r = i / 11, j = i - r * 11;
            *(ushort4*)&U[r * ASTR + 64 + j * 4] = *(const ushort4*)&nfh[(size_t)(r0 + r) * 44 + j * 4];
        }
        for (int i = tid; i < 7 * 32; i += 256) {
            int a = i >> 5, cc = i & 31;
            int n = min(nf0 + a, N_ATOMS - 1);
            *(ushort4*)&Sself[a * 128 + cc * 4] = *(const ushort4*)&selfout[(size_t)n * 128 + cc * 4];
        }
        __syncthreads();

        f32x4 acc[2][4];
#pragma unroll
        for (int rf = 0; rf < 2; ++rf)
#pragma unroll
            for (int ct = 0; ct < 4; ++ct) acc[rf][ct] = (f32x4){0, 0, 0, 0};
#pragma unroll
        for (int kc = 0; kc < 4; ++kc) {
            half8 a0 = *(half8*)&U[(rhalf * 32 + l16) * ASTR + kc * 32 + quad * 8];
            half8 a1 = *(half8*)&U[(rhalf * 32 + 16 + l16) * ASTR + kc * 32 + quad * 8];
#pragma unroll
            for (int ct = 0; ct < 4; ++ct) {
                acc[0][ct] = __builtin_amdgcn_mfma_f32_16x16x32_f16(a0, Bf[kc][ct], acc[0][ct], 0, 0, 0);
                acc[1][ct] = __builtin_amdgcn_mfma_f32_16x16x32_f16(a1, Bf[kc][ct], acc[1][ct], 0, 0, 0);
            }
        }
        __syncthreads();   // all MFMA reads of U done before P overwrites it

        // activation + write P halves (wave-uniform branch on chalf)
#pragma unroll
        for (int rf = 0; rf < 2; ++rf) {
            int rl0 = rhalf * 32 + rf * 16 + quad * 4;
#pragma unroll
            for (int ct = 0; ct < 4; ++ct) {
#pragma unroll
                for (int e = 0; e < 4; ++e) {
                    int rl = rl0 + e;
                    int al = (rl + r0m) / 12;
                    float v = acc[rf][ct][e] + (float)((f16*)Sself)[al * 128 + cidx[ct]];
                    float t = fmaf(Aff[ct], v, Bff[ct]);
                    if (c0w == 0) P1[rl * 64 + cidx[ct]] = (f16)sigmoidf_(t);
                    else          P2[rl * 64 + (cidx[ct] - 64)] = (f16)softplusf_(t);
                }
            }
        }
        __syncthreads();

        // product + m-reduce -> ns atomics
        {
            int f = tid & 63, rg = tid >> 6;
            int rs = rg * 16;
            float run = 0.0f;
            int cur = (r0 + rs) / 12;
            for (int r = rs; r < rs + 16; ++r) {
                int at = (r0 + r) / 12;
                if (at != cur) {
                    atomicAdd(&ns[(size_t)cur * 64 + f], run);
                    run = 0.0f; cur = at;
                }
                run = fmaf((float)P1[r * 64 + f], (float)P2[r * 64 + f], run);
            }
            atomicAdd(&ns[(size_t)cur * 64 + f], run);
        }
    }
}

// ---------------- bn2 stats over ns ----------------
__global__ __launch_bounds__(256) void k_bn2stats(const float* __restrict__ ns,
                                                  float* __restrict__ stats) {
    const int tid = threadIdx.x;
    const int f = tid & 63, ag = tid >> 6;
    float s = 0.0f, q = 0.0f;
    for (int n = blockIdx.x * 4 + ag; n < N_ATOMS; n += gridDim.x * 4) {
        float v = ns[(size_t)n * 64 + f];
        s += v; q = fmaf(v, v, q);
    }
    __shared__ float r[512];
    r[tid] = s; r[256 + tid] = q;
    __syncthreads();
    if (tid < 64) {
        float ss = r[tid] + r[tid + 64] + r[tid + 128] + r[tid + 192];
        float qq = r[256 + tid] + r[256 + tid + 64] + r[256 + tid + 128] + r[256 + tid + 192];
        atomicAdd(&stats[256 + tid], ss);
        atomicAdd(&stats[320 + tid], qq);
    }
}

// ---------------- convC: x = softplus(x + BN2(ns)) (fp32 + f16) --------------
__global__ __launch_bounds__(256) void k_convC(float* __restrict__ x,
                                               f16* __restrict__ xh,
                                               const float* __restrict__ ns,
                                               const float* __restrict__ g2,
                                               const float* __restrict__ be2,
                                               const float* __restrict__ stats) {
    const int i = blockIdx.x * 256 + threadIdx.x;
    const int f = i & 63;
    const float cnt = (float)N_ATOMS;
    float m = stats[256 + f] / cnt;
    float v = stats[320 + f] / cnt - m * m;
    float inv = rsqrtf(v + BN_EPS);
    float A = g2[f] * inv, B = be2[f] - A * m;
    float t = x[i] + fmaf(A, ns[i], B);
    float o = softplusf_(t);
    x[i] = o;
    xh[i] = (f16)o;
}

// ---------------- pool ----------------
__global__ __launch_bounds__(64) void k_pool(const float* __restrict__ x,
                                             const int* __restrict__ cidx,
                                             float* __restrict__ crys) {
    const int s = blockIdx.x;
    const int f = threadIdx.x;
    int lo = 0, hi = N_ATOMS;
    while (lo < hi) { int mid = (lo + hi) >> 1; if (cidx[mid] < s) lo = mid + 1; else hi = mid; }
    int lo2 = lo, hi2 = N_ATOMS;
    while (lo2 < hi2) { int mid = (lo2 + hi2) >> 1; if (cidx[mid] < s + 1) lo2 = mid + 1; else hi2 = mid; }
    float sum = 0.0f;
    for (int i = lo; i < lo2; ++i) sum += x[(size_t)i * 64 + f];
    float cnt = fmaxf((float)(lo2 - lo), 1.0f);
    crys[s * 64 + f] = sum / cnt;
}

// ---------------- head ----------------
__global__ __launch_bounds__(128) void k_head(const float* __restrict__ crys,
                                              const float* __restrict__ W1,
                                              const float* __restrict__ b1,
                                              const float* __restrict__ W2,
                                              const float* __restrict__ b2,
                                              float* __restrict__ out) {
    __shared__ float a_sh[64];
    __shared__ float r_sh[128];
    const int n = blockIdx.x;
    const int tid = threadIdx.x;
    if (tid < 64) a_sh[tid] = softplusf_(crys[n * 64 + tid]);
    __syncthreads();
    for (int p = 0; p < 2; ++p) {
        float acc = b1[p * 128 + tid];
#pragma unroll
        for (int f2 = 0; f2 < 64; ++f2)
            acc = fmaf(a_sh[f2], W1[(p * 64 + f2) * 128 + tid], acc);
        float contrib = softplusf_(acc) * W2[p * 128 + tid];
        r_sh[tid] = contrib;
        __syncthreads();
        for (int sft = 64; sft > 0; sft >>= 1) {
            if (tid < sft) r_sh[tid] += r_sh[tid + sft];
            __syncthreads();
        }
        if (tid == 0) out[n * 2 + p] = r_sh[0] + b2[p];
        __syncthreads();
    }
}

extern "C" void kernel_launch(void* const* d_in, const int* in_sizes, int n_in,
                              void* d_out, int out_size, void* d_ws, size_t ws_size,
                              hipStream_t stream) {
    const float* atom_fea = (const float*)d_in[0];
    const float* nbr_fea  = (const float*)d_in[1];
    const float* W_embed  = (const float*)d_in[2];
    const float* b_embed  = (const float*)d_in[3];
    const float* conv_W   = (const float*)d_in[4];
    const float* conv_b   = (const float*)d_in[5];
    const float* conv_g1  = (const float*)d_in[6];
    const float* conv_be1 = (const float*)d_in[7];
    const float* conv_g2  = (const float*)d_in[8];
    const float* conv_be2 = (const float*)d_in[9];
    const float* head_W1  = (const float*)d_in[10];
    const float* head_b1  = (const float*)d_in[11];
    const float* head_W2  = (const float*)d_in[12];
    const float* head_b2  = (const float*)d_in[13];
    const int*   nidx     = (const int*)d_in[14];
    const int*   cryst    = (const int*)d_in[15];

    char* w = (char*)d_ws;
    float* x       = (float*)w;                       //  33,554,432
    f16*   xh      = (f16*)(w + 33554432);            //  16,777,216
    f16*   nfh     = (f16*)(w + 50331648);            // 138,412,032
    f16*   selfout = (f16*)(w + 188743680);           //  33,554,432
    float* ns      = (float*)(w + 222298112);         //  33,554,432
    f16*   Wt2     = (f16*)(w + 255852544);           //      32,768
    float* stats   = (float*)(w + 255885312);         //       4,608
    const size_t required = 255885312ull + 4608ull;
    if (ws_size < required) {
        hipMemsetAsync(d_out, 0x7F, 4, stream);
        return;
    }

    hipMemsetAsync(stats, 0, NCONV * 384 * sizeof(float), stream);

    k_cvt_nbrf<<<N_ATOMS * M_NBR / 16, 256, 0, stream>>>(nbr_fea, nfh);
    k_embed<<<N_ATOMS * AF / 256, 256, 0, stream>>>(atom_fea, W_embed, b_embed, x, xh);

    for (int l = 0; l < NCONV; ++l) {
        float* st = stats + l * 384;
        const float* Wl = conv_W + (size_t)l * FIN * C2;
        k_selfW<<<N_ATOMS * C2 / 256, 256, 0, stream>>>(x, Wl, conv_b + l * C2, selfout);
        k_prepW2<<<C2 * KP / 256, 256, 0, stream>>>(Wl, Wt2);
        k_gstats<<<GGRID, 256, 0, stream>>>(xh, nfh, nidx, Wt2, selfout, st);
        hipMemsetAsync(ns, 0, (size_t)N_ATOMS * AF * sizeof(float), stream);
        k_gapply<<<GGRID, 256, 0, stream>>>(xh, nfh, nidx, Wt2, selfout,
                                            conv_g1 + l * C2, conv_be1 + l * C2, st, ns);
        k_bn2stats<<<1024, 256, 0, stream>>>(ns, st);
        k_convC<<<N_ATOMS * AF / 256, 256, 0, stream>>>(x, xh, ns, conv_g2 + l * AF, conv_be2 + l * AF, st);
    }

    float* crys = (float*)d_out + N0_CRYS * 2;   // crys_fea follows out
    k_pool<<<N0_CRYS, 64, 0, stream>>>(x, cryst, crys);
    k_head<<<N0_CRYS, 128, 0, stream>>>(crys, head_W1, head_b1, head_W2, head_b2, (float*)d_out);
}

// Round 6
// 3098.373 us; speedup vs baseline: 1.1583x; 1.1583x over previous
//
#include <hip/hip_runtime.h>

#define N_ATOMS 131072
#define M_NBR 12
#define ORIG_F 92
#define AF 64
#define NCONV 3
#define N0_CRYS 1024
#define FIN 169
#define C2 128
#define KP 128                       // K of nbr-part GEMM: 64 nbr + 44 nbrf + pad
#define BN_EPS 1e-5f
#define TILES (N_ATOMS * M_NBR / 64) // 24576 tiles of 64 rows
#define ASTR 136                     // LDS row stride (f16): 272B -> 16B aligned, 2-way banks

typedef _Float16 f16;
typedef _Float16 half8 __attribute__((ext_vector_type(8)));
typedef float f32x4 __attribute__((ext_vector_type(4)));

__device__ __forceinline__ float sigmoidf_(float t) {
    return 1.0f / (1.0f + __expf(-t));
}
__device__ __forceinline__ float softplusf_(float t) {
    return fmaxf(t, 0.0f) + __logf(1.0f + __expf(-fabsf(t)));
}

// ---------------- embed: x = atom_fea @ W_embed + b (fp32 + f16) -------------
__global__ __launch_bounds__(256) void k_embed(const float* __restrict__ af,
                                               const float* __restrict__ W,
                                               const float* __restrict__ b,
                                               float* __restrict__ x,
                                               f16* __restrict__ xh) {
    __shared__ float row[4][ORIG_F];
    const int tid = threadIdx.x;
    const int n0 = blockIdx.x * 4;
    for (int i = tid; i < 4 * ORIG_F; i += 256)
        row[i / ORIG_F][i % ORIG_F] = af[(size_t)n0 * ORIG_F + i];
    __syncthreads();
    const int a = tid >> 6, f = tid & 63;
    float acc = b[f];
    for (int k = 0; k < ORIG_F; ++k)
        acc = fmaf(row[a][k], W[k * AF + f], acc);
    size_t o = (size_t)(n0 + a) * AF + f;
    x[o] = acc;
    xh[o] = (f16)acc;
}

// ---------------- cvt nbr_fea -> f16 padded [N*M][44] (once) -----------------
__global__ __launch_bounds__(256) void k_cvt_nbrf(const float* __restrict__ nf,
                                                  f16* __restrict__ nfh) {
    const int r0 = blockIdx.x * 16;
    for (int i = threadIdx.x; i < 16 * 44; i += 256) {
        int r = i / 44, k = i - r * 44;
        size_t row = (size_t)(r0 + r);
        nfh[row * 44 + k] = (k < 41) ? (f16)nf[row * 41 + k] : (f16)0.0f;
    }
}

// ---------------- selfout[n][c] = x[n]·W[0:64][c] + b[c]  (f16) --------------
__global__ __launch_bounds__(256) void k_selfW(const float* __restrict__ x,
                                               const float* __restrict__ W,
                                               const float* __restrict__ b,
                                               f16* __restrict__ selfout) {
    int i = blockIdx.x * 256 + threadIdx.x;   // i < N*128
    int n = i >> 7, c = i & 127;
    float acc = b[c];
    for (int k = 0; k < 64; ++k)
        acc = fmaf(x[(size_t)n * 64 + k], W[k * C2 + c], acc);
    selfout[i] = (f16)acc;
}

// ---------------- Wt2[c][k]: nbr-part W^T, f16, K padded to 128 --------------
__global__ __launch_bounds__(256) void k_prepW2(const float* __restrict__ W,
                                                f16* __restrict__ Wt2) {
    int i = blockIdx.x * 256 + threadIdx.x;   // i < 128*128
    if (i >= C2 * KP) return;
    int c = i >> 7, k = i & 127;
    Wt2[i] = (k < 105) ? (f16)W[(k + 64) * C2 + c] : (f16)0.0f;
}

// ---------------- gemmf: gated = A @ Wt2^T + selfout  (+ BN1 stats) ----------
// block 256 = 4 waves; tile 64 rows x 128 cols; wave = (rhalf, chalf).
// A row gr = [xh[nidx[gr]] | nfh[gr] | 0-pad], K=128.
// C is transposed through Ash (reuse) and stored with 1KB-coalesced dwordx4.
__global__ __launch_bounds__(256) void k_gemmf(const f16* __restrict__ xh,
                                               const f16* __restrict__ nfh,
                                               const int* __restrict__ nidx,
                                               const f16* __restrict__ Wt2,
                                               const f16* __restrict__ selfout,
                                               f16* __restrict__ gated,
                                               float* __restrict__ stats) {
    __shared__ unsigned short Ash[64 * ASTR];
    __shared__ unsigned short Ssf[7 * 128];
    __shared__ float redS[128], redQ[128];

    const int tid = threadIdx.x;
    const int wv = tid >> 6, lane = tid & 63;
    const int quad = lane >> 4, l16 = lane & 15;
    const int rhalf = wv >> 1, c0w = (wv & 1) * 64;

    if (tid < 128) { redS[tid] = 0.0f; redQ[tid] = 0.0f; }

    half8 Bf[4][4];
    int cidx[4];
#pragma unroll
    for (int ct = 0; ct < 4; ++ct) {
        int c = c0w + ct * 16 + l16;
        cidx[ct] = c;
#pragma unroll
        for (int kc = 0; kc < 4; ++kc)
            Bf[kc][ct] = *(const half8*)&Wt2[c * KP + kc * 32 + quad * 8];
    }

    float ssum[4] = {0, 0, 0, 0}, ssq[4] = {0, 0, 0, 0};

    for (int rb = blockIdx.x; rb < TILES; rb += gridDim.x) {
        const int r0 = rb * 64;
        const int nf0 = r0 / 12, r0m = r0 - nf0 * 12;
        __syncthreads();   // prior iter's C-reads of Ash complete
        // gathered neighbor rows: cols 0..63
        for (int i = tid; i < 64 * 16; i += 256) {
            int r = i >> 4, sg = i & 15;
            int gi = nidx[r0 + r];
            *(ushort4*)&Ash[r * ASTR + sg * 4] = *(const ushort4*)&xh[(size_t)gi * 64 + sg * 4];
        }
        // nbr_fea rows: cols 64..107
        for (int i = tid; i < 64 * 11; i += 256) {
            int r = i / 11, j = i - r * 11;
            *(ushort4*)&Ash[r * ASTR + 64 + j * 4] = *(const ushort4*)&nfh[(size_t)(r0 + r) * 44 + j * 4];
        }
        // re-zero pad cols 108..127 (C pass overwrote them last iter)
        for (int i = tid; i < 64 * 5; i += 256) {
            int r = i / 5, t = i - r * 5;
            *(ushort4*)&Ash[r * ASTR + 108 + t * 4] = make_ushort4(0, 0, 0, 0);
        }
        // selfout rows for this tile's atoms
        for (int i = tid; i < 7 * 32; i += 256) {
            int a = i >> 5, cc = i & 31;
            int n = min(nf0 + a, N_ATOMS - 1);
            *(ushort4*)&Ssf[a * 128 + cc * 4] = *(const ushort4*)&selfout[(size_t)n * 128 + cc * 4];
        }
        __syncthreads();

        f32x4 acc[2][4];
#pragma unroll
        for (int rf = 0; rf < 2; ++rf)
#pragma unroll
            for (int ct = 0; ct < 4; ++ct) acc[rf][ct] = (f32x4){0, 0, 0, 0};
#pragma unroll
        for (int kc = 0; kc < 4; ++kc) {
            half8 a0 = *(half8*)&Ash[(rhalf * 32 + l16) * ASTR + kc * 32 + quad * 8];
            half8 a1 = *(half8*)&Ash[(rhalf * 32 + 16 + l16) * ASTR + kc * 32 + quad * 8];
#pragma unroll
            for (int ct = 0; ct < 4; ++ct) {
                acc[0][ct] = __builtin_amdgcn_mfma_f32_16x16x32_f16(a0, Bf[kc][ct], acc[0][ct], 0, 0, 0);
                acc[1][ct] = __builtin_amdgcn_mfma_f32_16x16x32_f16(a1, Bf[kc][ct], acc[1][ct], 0, 0, 0);
            }
        }
        __syncthreads();   // all waves' A reads done before C overwrites Ash

        // epilogue: add self, accumulate stats, write C (f16) into Ash
        f16* Cs = (f16*)Ash;
        const f16* Ss = (const f16*)Ssf;
#pragma unroll
        for (int rf = 0; rf < 2; ++rf) {
            int rl0 = rhalf * 32 + rf * 16 + quad * 4;
#pragma unroll
            for (int ct = 0; ct < 4; ++ct) {
#pragma unroll
                for (int e = 0; e < 4; ++e) {
                    int rl = rl0 + e;
                    int al = (rl + r0m) / 12;
                    float v = acc[rf][ct][e] + (float)Ss[al * 128 + cidx[ct]];
                    ssum[ct] += v;
                    ssq[ct] = fmaf(v, v, ssq[ct]);
                    Cs[rl * ASTR + cidx[ct]] = (f16)v;
                }
            }
        }
        __syncthreads();

        // coalesced store: wave w -> rows 16w..16w+15; per instr 4 rows = 1KB contiguous
        const int rgrp = lane >> 4, cseg = lane & 15;
#pragma unroll
        for (int k = 0; k < 4; ++k) {
            int row = wv * 16 + k * 4 + rgrp;
            uint4 v = *(uint4*)&Ash[row * ASTR + cseg * 8];
            *(uint4*)(gated + (size_t)(r0 + row) * 128 + cseg * 8) = v;
        }
    }

    // BN1 stats: quad-reduce, LDS-reduce, one global atomic per channel per block
#pragma unroll
    for (int ct = 0; ct < 4; ++ct) {
        float s = ssum[ct], q = ssq[ct];
        s += __shfl_xor(s, 16); s += __shfl_xor(s, 32);
        q += __shfl_xor(q, 16); q += __shfl_xor(q, 32);
        if (quad == 0) {
            atomicAdd(&redS[cidx[ct]], s);
            atomicAdd(&redQ[cidx[ct]], q);
        }
    }
    __syncthreads();
    if (tid < 128) {
        atomicAdd(&stats[tid], redS[tid]);
        atomicAdd(&stats[128 + tid], redQ[tid]);
    }
}

// ---------------- convB: BN1 + sigmoid*softplus + m-sum (+ BN2 stats) --------
// lane = channel-pair (2l, 2l+1); ushort2 loads fully coalesced; core half
// fetched from lane+32 via shfl_xor. One wave per atom.
__global__ __launch_bounds__(256) void k_convB(const f16* __restrict__ gated,
                                               const float* __restrict__ g1,
                                               const float* __restrict__ be1,
                                               float* __restrict__ stats,
                                               float* __restrict__ ns) {
    typedef _Float16 half2v __attribute__((ext_vector_type(2)));
    const int tid = threadIdx.x;
    const int wv = tid >> 6, lane = tid & 63;
    const int c0 = lane * 2;
    const int nwaves = gridDim.x * 4;
    const float cnt1 = (float)N_ATOMS * M_NBR;

    float m0 = stats[c0] / cnt1, m1 = stats[c0 + 1] / cnt1;
    float v0 = stats[128 + c0] / cnt1 - m0 * m0;
    float v1 = stats[128 + c0 + 1] / cnt1 - m1 * m1;
    float A0 = g1[c0] * rsqrtf(v0 + BN_EPS), B0 = be1[c0] - A0 * m0;
    float A1 = g1[c0 + 1] * rsqrtf(v1 + BN_EPS), B1 = be1[c0 + 1] - A1 * m1;

    float s0 = 0, q0 = 0, s1 = 0, q1 = 0;
    for (int n = blockIdx.x * 4 + wv; n < N_ATOMS; n += nwaves) {
        const f16* gp = gated + (size_t)n * (M_NBR * C2) + c0;
        float acc0 = 0.0f, acc1 = 0.0f;
#pragma unroll
        for (int m = 0; m < M_NBR; ++m) {
            half2v g = *(const half2v*)(gp + m * 128);
            float t0 = fmaf(A0, (float)g[0], B0);
            float t1 = fmaf(A1, (float)g[1], B1);
            float p0 = softplusf_(t0), p1 = softplusf_(t1);
            float cp0 = __shfl_xor(p0, 32);
            float cp1 = __shfl_xor(p1, 32);
            acc0 = fmaf(sigmoidf_(t0), cp0, acc0);
            acc1 = fmaf(sigmoidf_(t1), cp1, acc1);
        }
        if (lane < 32) {
            *(float2*)&ns[(size_t)n * 64 + c0] = make_float2(acc0, acc1);
            s0 += acc0; q0 = fmaf(acc0, acc0, q0);
            s1 += acc1; q1 = fmaf(acc1, acc1, q1);
        }
    }
    __shared__ float redS[64], redQ[64];
    if (tid < 64) { redS[tid] = 0.0f; redQ[tid] = 0.0f; }
    __syncthreads();
    if (lane < 32) {
        atomicAdd(&redS[c0], s0);     atomicAdd(&redQ[c0], q0);
        atomicAdd(&redS[c0 + 1], s1); atomicAdd(&redQ[c0 + 1], q1);
    }
    __syncthreads();
    if (tid < 64) {
        atomicAdd(&stats[256 + tid], redS[tid]);
        atomicAdd(&stats[320 + tid], redQ[tid]);
    }
}

// ---------------- convC: x = softplus(x + BN2(ns)) (fp32 + f16) --------------
__global__ __launch_bounds__(256) void k_convC(float* __restrict__ x,
                                               f16* __restrict__ xh,
                                               const float* __restrict__ ns,
                                               const float* __restrict__ g2,
                                               const float* __restrict__ be2,
                                               const float* __restrict__ stats) {
    const int i = blockIdx.x * 256 + threadIdx.x;
    const int f = i & 63;
    const float cnt = (float)N_ATOMS;
    float m = stats[256 + f] / cnt;
    float v = stats[320 + f] / cnt - m * m;
    float inv = rsqrtf(v + BN_EPS);
    float A = g2[f] * inv, B = be2[f] - A * m;
    float t = x[i] + fmaf(A, ns[i], B);
    float o = softplusf_(t);
    x[i] = o;
    xh[i] = (f16)o;
}

// ---------------- pool ----------------
__global__ __launch_bounds__(64) void k_pool(const float* __restrict__ x,
                                             const int* __restrict__ cidx,
                                             float* __restrict__ crys) {
    const int s = blockIdx.x;
    const int f = threadIdx.x;
    int lo = 0, hi = N_ATOMS;
    while (lo < hi) { int mid = (lo + hi) >> 1; if (cidx[mid] < s) lo = mid + 1; else hi = mid; }
    int lo2 = lo, hi2 = N_ATOMS;
    while (lo2 < hi2) { int mid = (lo2 + hi2) >> 1; if (cidx[mid] < s + 1) lo2 = mid + 1; else hi2 = mid; }
    float sum = 0.0f;
    for (int i = lo; i < lo2; ++i) sum += x[(size_t)i * 64 + f];
    float cnt = fmaxf((float)(lo2 - lo), 1.0f);
    crys[s * 64 + f] = sum / cnt;
}

// ---------------- head ----------------
__global__ __launch_bounds__(128) void k_head(const float* __restrict__ crys,
                                              const float* __restrict__ W1,
                                              const float* __restrict__ b1,
                                              const float* __restrict__ W2,
                                              const float* __restrict__ b2,
                                              float* __restrict__ out) {
    __shared__ float a_sh[64];
    __shared__ float r_sh[128];
    const int n = blockIdx.x;
    const int tid = threadIdx.x;
    if (tid < 64) a_sh[tid] = softplusf_(crys[n * 64 + tid]);
    __syncthreads();
    for (int p = 0; p < 2; ++p) {
        float acc = b1[p * 128 + tid];
#pragma unroll
        for (int f2 = 0; f2 < 64; ++f2)
            acc = fmaf(a_sh[f2], W1[(p * 64 + f2) * 128 + tid], acc);
        float contrib = softplusf_(acc) * W2[p * 128 + tid];
        r_sh[tid] = contrib;
        __syncthreads();
        for (int sft = 64; sft > 0; sft >>= 1) {
            if (tid < sft) r_sh[tid] += r_sh[tid + sft];
            __syncthreads();
        }
        if (tid == 0) out[n * 2 + p] = r_sh[0] + b2[p];
        __syncthreads();
    }
}

extern "C" void kernel_launch(void* const* d_in, const int* in_sizes, int n_in,
                              void* d_out, int out_size, void* d_ws, size_t ws_size,
                              hipStream_t stream) {
    const float* atom_fea = (const float*)d_in[0];
    const float* nbr_fea  = (const float*)d_in[1];
    const float* W_embed  = (const float*)d_in[2];
    const float* b_embed  = (const float*)d_in[3];
    const float* conv_W   = (const float*)d_in[4];
    const float* conv_b   = (const float*)d_in[5];
    const float* conv_g1  = (const float*)d_in[6];
    const float* conv_be1 = (const float*)d_in[7];
    const float* conv_g2  = (const float*)d_in[8];
    const float* conv_be2 = (const float*)d_in[9];
    const float* head_W1  = (const float*)d_in[10];
    const float* head_b1  = (const float*)d_in[11];
    const float* head_W2  = (const float*)d_in[12];
    const float* head_b2  = (const float*)d_in[13];
    const int*   nidx     = (const int*)d_in[14];
    const int*   cryst    = (const int*)d_in[15];

    char* w = (char*)d_ws;
    float* x       = (float*)w;                       //  33,554,432
    f16*   xh      = (f16*)(w + 33554432);            //  16,777,216
    f16*   nfh     = (f16*)(w + 50331648);            // 138,412,032
    f16*   selfout = (f16*)(w + 188743680);           //  33,554,432
    float* ns      = (float*)(w + 222298112);         //  33,554,432
    f16*   gated   = (f16*)(w + 255852544);           // 402,653,184
    f16*   Wt2     = (f16*)(w + 658505728);           //      32,768
    float* stats   = (float*)(w + 658538496);         //       4,608
    const size_t required = 658538496ull + 4608ull;
    if (ws_size < required) {
        hipMemsetAsync(d_out, 0x7F, 4, stream);
        return;
    }

    hipMemsetAsync(stats, 0, NCONV * 384 * sizeof(float), stream);

    k_cvt_nbrf<<<N_ATOMS * M_NBR / 16, 256, 0, stream>>>(nbr_fea, nfh);
    k_embed<<<N_ATOMS / 4, 256, 0, stream>>>(atom_fea, W_embed, b_embed, x, xh);

    for (int l = 0; l < NCONV; ++l) {
        float* st = stats + l * 384;
        const float* Wl = conv_W + (size_t)l * FIN * C2;
        k_selfW<<<N_ATOMS * C2 / 256, 256, 0, stream>>>(x, Wl, conv_b + l * C2, selfout);
        k_prepW2<<<C2 * KP / 256, 256, 0, stream>>>(Wl, Wt2);
        k_gemmf<<<1024, 256, 0, stream>>>(xh, nfh, nidx, Wt2, selfout, gated, st);
        k_convB<<<512, 256, 0, stream>>>(gated, conv_g1 + l * C2, conv_be1 + l * C2, st, ns);
        k_convC<<<N_ATOMS * AF / 256, 256, 0, stream>>>(x, xh, ns, conv_g2 + l * AF, conv_be2 + l * AF, st);
    }

    float* crys = (float*)d_out + N0_CRYS * 2;   // crys_fea follows out
    k_pool<<<N0_CRYS, 64, 0, stream>>>(x, cryst, crys);
    k_head<<<N0_CRYS, 128, 0, stream>>>(crys, head_W1, head_b1, head_W2, head_b2, (float*)d_out);
}